// Round 4
// baseline (22.452 us; speedup 1.0000x reference)
//
#include <hip/hip_runtime.h>
#include <stdint.h>

#define S 2048
#define B 256
#define H 8
#define NPER 12
#define NPOS 11
#define THRESH 4

typedef unsigned long long u64;
typedef uint32_t u32;

// ws layout:
//  [0,       65536)   packed_tokens : S*4 u64   (64 KB)
//  [65536,   98304)   qc_u16        : S*8 u16   (32 KB)
//  [98304,  131072)   kc_u16        : S*8 u16   (32 KB)
//  [131072, 163840)   pc_u16        : S*8 u16   (32 KB)
//  [163840, 167936)   packed_table  : 512 u64   ( 4 KB)

// blocks 0..S-1: per-row token pack + q/k/p contribs; blocks S..S+1: table bitpack
__global__ void prep_kernel(const int* __restrict__ tokens,
                            const int* __restrict__ conn,
                            const int* __restrict__ table,
                            u64* __restrict__ packed_tokens,
                            uint16_t* __restrict__ qc,
                            uint16_t* __restrict__ kc,
                            uint16_t* __restrict__ pc,
                            u64* __restrict__ ptab) {
    const int bi = blockIdx.x;
    const int tid = threadIdx.x;

    if (bi >= S) {
        int k = (bi - S) * 256 + tid;          // 0..511
        int h = k >> 6, w = k & 63;
        const int* src = table + h * 4096 + w * 64;
        u64 v = 0;
        #pragma unroll 8
        for (int b = 0; b < 64; ++b) v |= (u64)(src[b] & 1) << b;
        ptab[k] = v;
        return;
    }

    __shared__ u64 srow[4];
    const int i = bi;
    const int lane = tid & 63, wave = tid >> 6;

    int t = tokens[i * B + tid];
    u64 m = __ballot(t != 0);
    if (lane == 0) {
        srow[wave] = m;
        packed_tokens[i * 4 + wave] = m;
    }
    __syncthreads();

    if (tid < H) {
        int h = tid;
        int q = 0, k = 0, p = 0;
        #pragma unroll
        for (int n = 0; n < NPER; ++n) {
            int c = conn[h * NPER + n];
            if (c < B) {
                q |= (int)((srow[c >> 6] >> (c & 63)) & 1) << n;
            } else if (c < 2 * B) {
                int cc = c - B;
                k |= (int)((srow[cc >> 6] >> (cc & 63)) & 1) << n;
            } else {
                int idx = c - 2 * B;            // [0, NPOS)
                p |= ((i >> idx) & 1) << n;
            }
        }
        qc[i * 8 + h] = (uint16_t)q;
        kc[i * 8 + h] = (uint16_t)k;
        pc[i * 8 + h] = (uint16_t)p;
    }
}

// 8 table lookups for one packed address pair (a0: heads 0-3, a1: heads 4-7)
__device__ __forceinline__ int vote8(const u32* s_tab, u64 a0, u64 a1) {
    int v = 0;
    #pragma unroll
    for (int h = 0; h < 4; ++h) {
        { u32 w = (u32)(a0 >> (16 * h + 5)) & 127;
          v += (int)((s_tab[h * 128 + w] >> ((u32)(a0 >> (16 * h)) & 31)) & 1); }
        { u32 w = (u32)(a1 >> (16 * h + 5)) & 127;
          v += (int)((s_tab[(h + 4) * 128 + w] >> ((u32)(a1 >> (16 * h)) & 31)) & 1); }
    }
    return v;
}

__launch_bounds__(256, 4)
__global__ void main_kernel(const u64* __restrict__ packed_tokens,
                            const uint16_t* __restrict__ qc,
                            const uint16_t* __restrict__ kc,
                            const uint16_t* __restrict__ pc,
                            const u64* __restrict__ ptab,
                            int* __restrict__ out) {
    __shared__ u32 s_tab[1024];                 // head h at [h*128, (h+1)*128)
    __shared__ u64 s_red[4][9];                 // per-wave: bx0..3, sx0..3, keys

    const int tid = threadIdx.x;
    const int lane = tid & 63, wave = tid >> 6;

    ((uint4*)s_tab)[tid] = ((const uint4*)ptab)[tid];   // 4 KB table -> LDS
    __syncthreads();

    const int b  = blockIdx.x;      // 0..1023
    const int is = b;               // small row
    const int ib = 2047 - b;        // big row (>= 1024)

    const u64* qvb = (const u64*)(qc + ib * 8);
    const u64 qb0 = qvb[0], qb1 = qvb[1];
    const u64* qvs = (const u64*)(qc + is * 8);
    const u64 qs0 = qvs[0], qs1 = qvs[1];

    u64 bx0 = 0, bx1 = 0, bx2 = 0, bx3 = 0;    // big-row parity acc
    u64 sx0 = 0, sx1 = 0, sx2 = 0, sx3 = 0;    // small-row parity acc
    int bbv = -1, bbj = 0, sbv = -1, sbj = 0;

    const int niter = (ib + 512) >> 9;          // ceil((ib+1)/512)
    for (int it = 0; it < niter; ++it) {
        const int ja = tid + (it << 9);
        const int jb = ja + 256;
        const int jca = min(ja, ib), jcb = min(jb, ib);

        // loads shared by both rows
        const ulonglong2 kA  = *(const ulonglong2*)(kc + jca * 8);
        const ulonglong2 kB  = *(const ulonglong2*)(kc + jcb * 8);
        const ulonglong2 tA0 = *(const ulonglong2*)(packed_tokens + jca * 4);
        const ulonglong2 tA1 = *(const ulonglong2*)(packed_tokens + jca * 4 + 2);
        const ulonglong2 tB0 = *(const ulonglong2*)(packed_tokens + jcb * 4);
        const ulonglong2 tB1 = *(const ulonglong2*)(packed_tokens + jcb * 4 + 2);

        // ---- big row ----
        {
            const ulonglong2 pA = *(const ulonglong2*)(pc + (ib - jca) * 8);
            const ulonglong2 pB = *(const ulonglong2*)(pc + (ib - jcb) * 8);
            const int vA = vote8(s_tab, qb0 + kA.x + pA.x, qb1 + kA.y + pA.y);
            const int vB = vote8(s_tab, qb0 + kB.x + pB.x, qb1 + kB.y + pB.y);
            const bool actA = (ja <= ib), actB = (jb <= ib);
            const u64 mA = (actA && vA >= THRESH) ? ~0ull : 0ull;
            const u64 mB = (actB && vB >= THRESH) ? ~0ull : 0ull;
            bx0 ^= (tA0.x & mA) ^ (tB0.x & mB);
            bx1 ^= (tA0.y & mA) ^ (tB0.y & mB);
            bx2 ^= (tA1.x & mA) ^ (tB1.x & mB);
            bx3 ^= (tA1.y & mA) ^ (tB1.y & mB);
            const int kvA = actA ? vA : -1;
            const int kvB = actB ? vB : -1;
            if (kvA > bbv) { bbv = kvA; bbj = ja; }
            if (kvB > bbv) { bbv = kvB; bbj = jb; }
        }

        // ---- small row (block-uniform skip when tile beyond is) ----
        if ((it << 9) <= is) {
            const int jsa = min(ja, is), jsb = min(jb, is);
            const ulonglong2 pA = *(const ulonglong2*)(pc + (is - jsa) * 8);
            const ulonglong2 pB = *(const ulonglong2*)(pc + (is - jsb) * 8);
            // kA/kB/tokens reuse: garbage when ja>is but masked below
            const int vA = vote8(s_tab, qs0 + kA.x + pA.x, qs1 + kA.y + pA.y);
            const int vB = vote8(s_tab, qs0 + kB.x + pB.x, qs1 + kB.y + pB.y);
            const bool actA = (ja <= is), actB = (jb <= is);
            const u64 mA = (actA && vA >= THRESH) ? ~0ull : 0ull;
            const u64 mB = (actB && vB >= THRESH) ? ~0ull : 0ull;
            sx0 ^= (tA0.x & mA) ^ (tB0.x & mB);
            sx1 ^= (tA0.y & mA) ^ (tB0.y & mB);
            sx2 ^= (tA1.x & mA) ^ (tB1.x & mB);
            sx3 ^= (tA1.y & mA) ^ (tB1.y & mB);
            const int kvA = actA ? vA : -1;
            const int kvB = actB ? vB : -1;
            if (kvA > sbv) { sbv = kvA; sbj = ja; }
            if (kvB > sbv) { sbv = kvB; sbj = jb; }
        }
    }

    // keys: higher vote wins; tie -> smaller j (matches argmax first-occurrence)
    u32 bkey = (u32)(((bbv + 1) << 16) | (2047 - bbj));
    u32 skey = (u32)(((sbv + 1) << 16) | (2047 - sbj));

    #pragma unroll
    for (int off = 32; off > 0; off >>= 1) {
        bkey = max(bkey, (u32)__shfl_xor((int)bkey, off));
        skey = max(skey, (u32)__shfl_xor((int)skey, off));
        bx0 ^= __shfl_xor(bx0, off); bx1 ^= __shfl_xor(bx1, off);
        bx2 ^= __shfl_xor(bx2, off); bx3 ^= __shfl_xor(bx3, off);
        sx0 ^= __shfl_xor(sx0, off); sx1 ^= __shfl_xor(sx1, off);
        sx2 ^= __shfl_xor(sx2, off); sx3 ^= __shfl_xor(sx3, off);
    }

    if (lane == 0) {
        s_red[wave][0] = bx0; s_red[wave][1] = bx1;
        s_red[wave][2] = bx2; s_red[wave][3] = bx3;
        s_red[wave][4] = sx0; s_red[wave][5] = sx1;
        s_red[wave][6] = sx2; s_red[wave][7] = sx3;
        s_red[wave][8] = ((u64)bkey << 32) | skey;
    }
    __syncthreads();

    const int widx = tid >> 6, bitb = tid & 63;
    u64 xwb = s_red[0][widx]     ^ s_red[1][widx]     ^ s_red[2][widx]     ^ s_red[3][widx];
    u64 xws = s_red[0][4 + widx] ^ s_red[1][4 + widx] ^ s_red[2][4 + widx] ^ s_red[3][4 + widx];
    u64 kk0 = s_red[0][8], kk1 = s_red[1][8], kk2 = s_red[2][8], kk3 = s_red[3][8];
    const u32 fkb = max(max((u32)(kk0 >> 32), (u32)(kk1 >> 32)),
                        max((u32)(kk2 >> 32), (u32)(kk3 >> 32)));
    const u32 fks = max(max((u32)kk0, (u32)kk1), max((u32)kk2, (u32)kk3));

    // any_included == (best vote >= THRESH); key>>16 == bestv+1
    int ob, os;
    if ((fkb >> 16) > THRESH) {
        ob = (int)((xwb >> bitb) & 1);
    } else {
        const int bj = 2047 - (int)(fkb & 0xFFFF);
        ob = (int)((packed_tokens[bj * 4 + widx] >> bitb) & 1);
    }
    if ((fks >> 16) > THRESH) {
        os = (int)((xws >> bitb) & 1);
    } else {
        const int bj = 2047 - (int)(fks & 0xFFFF);
        os = (int)((packed_tokens[bj * 4 + widx] >> bitb) & 1);
    }
    out[ib * B + tid] = ob;
    out[is * B + tid] = os;
}

extern "C" void kernel_launch(void* const* d_in, const int* in_sizes, int n_in,
                              void* d_out, int out_size, void* d_ws, size_t ws_size,
                              hipStream_t stream) {
    const int* tokens = (const int*)d_in[0];
    const int* conn   = (const int*)d_in[1];
    const int* table  = (const int*)d_in[2];
    int* out = (int*)d_out;

    uint8_t* ws = (uint8_t*)d_ws;
    u64* packed_tokens = (u64*)(ws);
    uint16_t* qc = (uint16_t*)(ws + 65536);
    uint16_t* kc = (uint16_t*)(ws + 98304);
    uint16_t* pc = (uint16_t*)(ws + 131072);
    u64* ptab    = (u64*)(ws + 163840);

    prep_kernel<<<S + 2, 256, 0, stream>>>(tokens, conn, table,
                                           packed_tokens, qc, kc, pc, ptab);
    main_kernel<<<S / 2, 256, 0, stream>>>(packed_tokens, qc, kc, pc, ptab, out);
}

// Round 5
// 22.287 us; speedup vs baseline: 1.0074x; 1.0074x over previous
//
#include <hip/hip_runtime.h>
#include <stdint.h>

#define S 2048
#define B 256
#define H 8
#define NPER 12
#define NPOS 11
#define THRESH 4

typedef unsigned long long u64;
typedef uint32_t u32;

// ws layout:
//  [0,       65536)   packed_tokens : S*4 u64   (64 KB)
//  [65536,   98304)   qc_u16        : S*8 u16   (32 KB)
//  [98304,  131072)   kc_u16        : S*8 u16   (32 KB)
//  [131072, 163840)   pc_u16        : S*8 u16   (32 KB)
//  [163840, 167936)   packed_table  : 512 u64   ( 4 KB)

// blocks 0..S-1: per-row token pack + q/k/p contribs; blocks S..S+1: table bitpack
__global__ void prep_kernel(const int* __restrict__ tokens,
                            const int* __restrict__ conn,
                            const int* __restrict__ table,
                            u64* __restrict__ packed_tokens,
                            uint16_t* __restrict__ qc,
                            uint16_t* __restrict__ kc,
                            uint16_t* __restrict__ pc,
                            u64* __restrict__ ptab) {
    const int bi = blockIdx.x;
    const int tid = threadIdx.x;

    if (bi >= S) {
        int k = (bi - S) * 256 + tid;          // 0..511
        int h = k >> 6, w = k & 63;
        const int* src = table + h * 4096 + w * 64;
        u64 v = 0;
        #pragma unroll 8
        for (int b = 0; b < 64; ++b) v |= (u64)(src[b] & 1) << b;
        ptab[k] = v;
        return;
    }

    __shared__ u64 srow[4];
    const int i = bi;
    const int lane = tid & 63, wave = tid >> 6;

    int t = tokens[i * B + tid];
    u64 m = __ballot(t != 0);
    if (lane == 0) {
        srow[wave] = m;
        packed_tokens[i * 4 + wave] = m;
    }
    __syncthreads();

    if (tid < H) {
        int h = tid;
        int q = 0, k = 0, p = 0;
        #pragma unroll
        for (int n = 0; n < NPER; ++n) {
            int c = conn[h * NPER + n];
            if (c < B) {
                q |= (int)((srow[c >> 6] >> (c & 63)) & 1) << n;
            } else if (c < 2 * B) {
                int cc = c - B;
                k |= (int)((srow[cc >> 6] >> (cc & 63)) & 1) << n;
            } else {
                int idx = c - 2 * B;            // [0, NPOS)
                p |= ((i >> idx) & 1) << n;
            }
        }
        qc[i * 8 + h] = (uint16_t)q;
        kc[i * 8 + h] = (uint16_t)k;
        pc[i * 8 + h] = (uint16_t)p;
    }
}

// 8 table lookups for one packed address pair (a0: heads 0-3, a1: heads 4-7)
__device__ __forceinline__ int vote8(const u32* s_tab, u64 a0, u64 a1) {
    int v = 0;
    #pragma unroll
    for (int h = 0; h < 4; ++h) {
        { u32 w = (u32)(a0 >> (16 * h + 5)) & 127;
          v += (int)((s_tab[h * 128 + w] >> ((u32)(a0 >> (16 * h)) & 31)) & 1); }
        { u32 w = (u32)(a1 >> (16 * h + 5)) & 127;
          v += (int)((s_tab[(h + 4) * 128 + w] >> ((u32)(a1 >> (16 * h)) & 31)) & 1); }
    }
    return v;
}

__launch_bounds__(256)
__global__ void main_kernel(const u64* __restrict__ packed_tokens,
                            const uint16_t* __restrict__ qc,
                            const uint16_t* __restrict__ kc,
                            const uint16_t* __restrict__ pc,
                            const u64* __restrict__ ptab,
                            int* __restrict__ out) {
    __shared__ u32 s_tab[1024];                 // head h at [h*128, (h+1)*128)
    __shared__ ulonglong2 s_pc[2048];           // full pc table, 32 KB
    __shared__ u64 s_red[4][9];                 // per-wave: bx0..3, sx0..3, keys

    const int tid = threadIdx.x;
    const int lane = tid & 63, wave = tid >> 6;

    ((uint4*)s_tab)[tid] = ((const uint4*)ptab)[tid];   // 4 KB table -> LDS
    {
        const ulonglong2* pcv = (const ulonglong2*)pc;
        #pragma unroll
        for (int k = 0; k < 8; ++k)
            s_pc[tid + k * 256] = pcv[tid + k * 256];   // 32 KB pc -> LDS
    }
    __syncthreads();

    const int b  = blockIdx.x;      // 0..1023
    const int is = b;               // small row
    const int ib = 2047 - b;        // big row (>= 1024)

    const u64* qvb = (const u64*)(qc + ib * 8);
    const u64 qb0 = qvb[0], qb1 = qvb[1];
    const u64* qvs = (const u64*)(qc + is * 8);
    const u64 qs0 = qvs[0], qs1 = qvs[1];

    u64 bx0 = 0, bx1 = 0, bx2 = 0, bx3 = 0;    // big-row parity acc
    u64 sx0 = 0, sx1 = 0, sx2 = 0, sx3 = 0;    // small-row parity acc
    int bbv = -1, bbj = 0, sbv = -1, sbj = 0;

    const int niter = (ib + 512) >> 9;          // ceil((ib+1)/512)
    for (int it = 0; it < niter; ++it) {
        const int ja = tid + (it << 9);
        const int jb = ja + 256;
        const int jca = min(ja, ib), jcb = min(jb, ib);

        // global loads shared by both rows (L2-resident, coalesced)
        const ulonglong2 kA  = *(const ulonglong2*)(kc + jca * 8);
        const ulonglong2 kB  = *(const ulonglong2*)(kc + jcb * 8);
        const ulonglong2 tA0 = *(const ulonglong2*)(packed_tokens + jca * 4);
        const ulonglong2 tA1 = *(const ulonglong2*)(packed_tokens + jca * 4 + 2);
        const ulonglong2 tB0 = *(const ulonglong2*)(packed_tokens + jcb * 4);
        const ulonglong2 tB1 = *(const ulonglong2*)(packed_tokens + jcb * 4 + 2);

        // ---- big row ----
        {
            const ulonglong2 pA = s_pc[ib - jca];
            const ulonglong2 pB = s_pc[ib - jcb];
            const int vA = vote8(s_tab, qb0 + kA.x + pA.x, qb1 + kA.y + pA.y);
            const int vB = vote8(s_tab, qb0 + kB.x + pB.x, qb1 + kB.y + pB.y);
            const bool actA = (ja <= ib), actB = (jb <= ib);
            const u64 mA = (actA && vA >= THRESH) ? ~0ull : 0ull;
            const u64 mB = (actB && vB >= THRESH) ? ~0ull : 0ull;
            bx0 ^= (tA0.x & mA) ^ (tB0.x & mB);
            bx1 ^= (tA0.y & mA) ^ (tB0.y & mB);
            bx2 ^= (tA1.x & mA) ^ (tB1.x & mB);
            bx3 ^= (tA1.y & mA) ^ (tB1.y & mB);
            const int kvA = actA ? vA : -1;
            const int kvB = actB ? vB : -1;
            if (kvA > bbv) { bbv = kvA; bbj = ja; }
            if (kvB > bbv) { bbv = kvB; bbj = jb; }
        }

        // ---- small row (block-uniform skip when tile fully beyond is) ----
        if ((it << 9) <= is) {
            const int jsa = min(ja, is), jsb = min(jb, is);
            const ulonglong2 pA = s_pc[is - jsa];
            const ulonglong2 pB = s_pc[is - jsb];
            const int vA = vote8(s_tab, qs0 + kA.x + pA.x, qs1 + kA.y + pA.y);
            const int vB = vote8(s_tab, qs0 + kB.x + pB.x, qs1 + kB.y + pB.y);
            const bool actA = (ja <= is), actB = (jb <= is);
            const u64 mA = (actA && vA >= THRESH) ? ~0ull : 0ull;
            const u64 mB = (actB && vB >= THRESH) ? ~0ull : 0ull;
            sx0 ^= (tA0.x & mA) ^ (tB0.x & mB);
            sx1 ^= (tA0.y & mA) ^ (tB0.y & mB);
            sx2 ^= (tA1.x & mA) ^ (tB1.x & mB);
            sx3 ^= (tA1.y & mA) ^ (tB1.y & mB);
            const int kvA = actA ? vA : -1;
            const int kvB = actB ? vB : -1;
            if (kvA > sbv) { sbv = kvA; sbj = ja; }
            if (kvB > sbv) { sbv = kvB; sbj = jb; }
        }
    }

    // keys: higher vote wins; tie -> smaller j (matches argmax first-occurrence)
    u32 bkey = (u32)(((bbv + 1) << 16) | (2047 - bbj));
    u32 skey = (u32)(((sbv + 1) << 16) | (2047 - sbj));

    #pragma unroll
    for (int off = 32; off > 0; off >>= 1) {
        bkey = max(bkey, (u32)__shfl_xor((int)bkey, off));
        skey = max(skey, (u32)__shfl_xor((int)skey, off));
        bx0 ^= __shfl_xor(bx0, off); bx1 ^= __shfl_xor(bx1, off);
        bx2 ^= __shfl_xor(bx2, off); bx3 ^= __shfl_xor(bx3, off);
        sx0 ^= __shfl_xor(sx0, off); sx1 ^= __shfl_xor(sx1, off);
        sx2 ^= __shfl_xor(sx2, off); sx3 ^= __shfl_xor(sx3, off);
    }

    if (lane == 0) {
        s_red[wave][0] = bx0; s_red[wave][1] = bx1;
        s_red[wave][2] = bx2; s_red[wave][3] = bx3;
        s_red[wave][4] = sx0; s_red[wave][5] = sx1;
        s_red[wave][6] = sx2; s_red[wave][7] = sx3;
        s_red[wave][8] = ((u64)bkey << 32) | skey;
    }
    __syncthreads();

    const int widx = tid >> 6, bitb = tid & 63;
    u64 xwb = s_red[0][widx]     ^ s_red[1][widx]     ^ s_red[2][widx]     ^ s_red[3][widx];
    u64 xws = s_red[0][4 + widx] ^ s_red[1][4 + widx] ^ s_red[2][4 + widx] ^ s_red[3][4 + widx];
    u64 kk0 = s_red[0][8], kk1 = s_red[1][8], kk2 = s_red[2][8], kk3 = s_red[3][8];
    const u32 fkb = max(max((u32)(kk0 >> 32), (u32)(kk1 >> 32)),
                        max((u32)(kk2 >> 32), (u32)(kk3 >> 32)));
    const u32 fks = max(max((u32)kk0, (u32)kk1), max((u32)kk2, (u32)kk3));

    // any_included == (best vote >= THRESH); key>>16 == bestv+1
    int ob, os;
    if ((fkb >> 16) > THRESH) {
        ob = (int)((xwb >> bitb) & 1);
    } else {
        const int bj = 2047 - (int)(fkb & 0xFFFF);
        ob = (int)((packed_tokens[bj * 4 + widx] >> bitb) & 1);
    }
    if ((fks >> 16) > THRESH) {
        os = (int)((xws >> bitb) & 1);
    } else {
        const int bj = 2047 - (int)(fks & 0xFFFF);
        os = (int)((packed_tokens[bj * 4 + widx] >> bitb) & 1);
    }
    out[ib * B + tid] = ob;
    out[is * B + tid] = os;
}

extern "C" void kernel_launch(void* const* d_in, const int* in_sizes, int n_in,
                              void* d_out, int out_size, void* d_ws, size_t ws_size,
                              hipStream_t stream) {
    const int* tokens = (const int*)d_in[0];
    const int* conn   = (const int*)d_in[1];
    const int* table  = (const int*)d_in[2];
    int* out = (int*)d_out;

    uint8_t* ws = (uint8_t*)d_ws;
    u64* packed_tokens = (u64*)(ws);
    uint16_t* qc = (uint16_t*)(ws + 65536);
    uint16_t* kc = (uint16_t*)(ws + 98304);
    uint16_t* pc = (uint16_t*)(ws + 131072);
    u64* ptab    = (u64*)(ws + 163840);

    prep_kernel<<<S + 2, 256, 0, stream>>>(tokens, conn, table,
                                           packed_tokens, qc, kc, pc, ptab);
    main_kernel<<<S / 2, 256, 0, stream>>>(packed_tokens, qc, kc, pc, ptab, out);
}